// Round 11
// baseline (129.318 us; speedup 1.0000x reference)
//
#include <hip/hip_runtime.h>
#include <hip/hip_bf16.h>
#include <math.h>

#define Bsz 8
#define Hh 64
#define Ww 64
#define Cc 256
#define Nn 64
#define Ll 4096      /* Hh*Ww */
#define EPSf 1e-5f

typedef __bf16 v8bf __attribute__((ext_vector_type(8)));
typedef float  f32x4 __attribute__((ext_vector_type(4)));

__device__ __forceinline__ float ad_val(float a, float snr) {
    float s = fminf(fmaxf(snr, 0.f), 1.f);
    float scale = 0.6f + 0.4f * s;
    float v = tanhf(a) * scale;
    return fminf(fmaxf(v, -0.99f), 0.99f);
}

// K0: weights -> bf16 MFMA B-fragment order. (R2-proven, verbatim.)
__global__ __launch_bounds__(256) void k0_weights(
    const float* __restrict__ Win, const float* __restrict__ Wout,
    const float* __restrict__ Bp, const float* __restrict__ Cp,
    __bf16* __restrict__ Wh, __bf16* __restrict__ Wl,
    __bf16* __restrict__ Woh, __bf16* __restrict__ Wol,
    float* __restrict__ WB)
{
    const int t = threadIdx.x;
    const int blk = blockIdx.x;
    if (blk < 4) {
        for (int idx = blk * 512 + t; idx < blk * 512 + 512; idx += 256) {
            int tile = idx >> 6, lane = idx & 63;
            int kt = tile >> 2, nt = tile & 3;
            int q = lane >> 4, n = nt * 16 + (lane & 15);
            #pragma unroll
            for (int j = 0; j < 8; ++j) {
                int k = kt * 32 + q * 8 + j;
                float w = Win[n * Cc + k];
                __bf16 h = (__bf16)w;
                Wh[idx * 8 + j] = h;
                Wl[idx * 8 + j] = (__bf16)(w - (float)h);
            }
        }
    } else if (blk < 8) {
        for (int idx = (blk - 4) * 512 + t; idx < (blk - 4) * 512 + 512; idx += 256) {
            int tile = idx >> 6, lane = idx & 63;
            int kt = tile >> 4, ntg = tile & 15;
            int q = lane >> 4, c = ntg * 16 + (lane & 15);
            #pragma unroll
            for (int j = 0; j < 8; ++j) {
                int k = kt * 32 + q * 8 + j;
                float w = Wout[c * Nn + k] * 0.25f * Cp[k];
                __bf16 h = (__bf16)w;
                Woh[idx * 8 + j] = h;
                Wol[idx * 8 + j] = (__bf16)(w - (float)h);
            }
        }
    } else {
        __shared__ float wtmp[256];
        int n = t >> 2, qd = t & 3;
        float s = 0.f;
        const float* wr = Win + (long)n * Cc + qd * 64;
        for (int i = 0; i < 64; ++i) s += wr[i];
        wtmp[t] = s;
        __syncthreads();
        if (t < 64)
            WB[t] = (wtmp[t*4] + wtmp[t*4+1] + wtmp[t*4+2] + wtmp[t*4+3]) * Bp[t];
    }
}

// K1: MFMA input projection, LN stats fused into GEMM A-loads (R9-green
// arithmetic verbatim) — NOW with ALL 16 x-loads issued as one burst into
// registers before the MFMA loop (1 exposed latency instead of 8).
// Bit-identical values and MFMA order. 512 blocks x 256 thr.
__global__ __launch_bounds__(256) void k1_ln_gemm(
    const float* __restrict__ x, const __bf16* __restrict__ Wh,
    const __bf16* __restrict__ Wl, const float* __restrict__ Bp,
    const float* __restrict__ WB, const float* __restrict__ A,
    const float* __restrict__ snr,
    float* __restrict__ Bu, float* __restrict__ E,
    float* __restrict__ Mst, float* __restrict__ Sst)
{
    __shared__ float tile[64 * 68];
    __shared__ float pfs[4][64], pbs[4][64];
    const int t = threadIdx.x;
    const int lane = t & 63;
    const int wv = __builtin_amdgcn_readfirstlane(t >> 6);
    const long pbase = (long)blockIdx.x * 64;
    const float* xt = x + pbase * Cc;

    const int q = lane >> 4;
    const int mi = lane & 15;
    const float* xa = xt + (long)(wv * 16 + mi) * Cc + q * 8;

    // load burst: all 64 x floats for this lane (16 independent float4 loads)
    float4 axv[16];
    #pragma unroll
    for (int kt = 0; kt < 8; ++kt) {
        axv[kt * 2]     = *(const float4*)(xa + kt * 32);
        axv[kt * 2 + 1] = *(const float4*)(xa + kt * 32 + 4);
    }

    f32x4 acc[4];
    #pragma unroll
    for (int nt = 0; nt < 4; ++nt) acc[nt] = (f32x4){0.f, 0.f, 0.f, 0.f};
    float sacc = 0.f, qacc = 0.f;       // LN partial sums for row wv*16+mi

    #pragma unroll
    for (int kt = 0; kt < 8; ++kt) {
        float4 a0 = axv[kt * 2];
        float4 a1 = axv[kt * 2 + 1];
        float av[8] = {a0.x, a0.y, a0.z, a0.w, a1.x, a1.y, a1.z, a1.w};
        v8bf ah, al;
        #pragma unroll
        for (int j = 0; j < 8; ++j) {
            sacc += av[j];
            qacc = fmaf(av[j], av[j], qacc);
            __bf16 h = (__bf16)av[j];
            ah[j] = h;
            al[j] = (__bf16)(av[j] - (float)h);
        }
        #pragma unroll
        for (int nt = 0; nt < 4; ++nt) {
            v8bf bh = *(const v8bf*)(Wh + ((long)(kt * 4 + nt) * 64 + lane) * 8);
            v8bf bl = *(const v8bf*)(Wl + ((long)(kt * 4 + nt) * 64 + lane) * 8);
            acc[nt] = __builtin_amdgcn_mfma_f32_16x16x32_bf16(ah, bh, acc[nt], 0, 0, 0);
            acc[nt] = __builtin_amdgcn_mfma_f32_16x16x32_bf16(al, bh, acc[nt], 0, 0, 0);
            acc[nt] = __builtin_amdgcn_mfma_f32_16x16x32_bf16(ah, bl, acc[nt], 0, 0, 0);
        }
    }

    // finish LN stats: reduce over the 4 lanes (q=0..3) holding row wv*16+mi
    sacc += __shfl_xor(sacc, 16);
    qacc += __shfl_xor(qacc, 16);
    sacc += __shfl_xor(sacc, 32);
    qacc += __shfl_xor(qacc, 32);
    float m_row = sacc * (1.f/256.f);
    float var = fmaxf(qacc * (1.f/256.f) - m_row * m_row, 0.f);
    float r1 = rsqrtf(var + EPSf);
    float v2 = var / (var + EPSf);
    float sc_row = r1 * rsqrtf(v2 + EPSf);
    if (lane < 16) {                     // q==0 lanes own rows wv*16+mi
        Mst[pbase + wv * 16 + mi] = m_row;
        Sst[pbase + wv * 16 + mi] = sc_row;
    }

    #pragma unroll
    for (int nt = 0; nt < 4; ++nt) {
        int n = nt * 16 + mi;
        float bpn = Bp[n];
        float wbn = WB[n];
        #pragma unroll
        for (int reg = 0; reg < 4; ++reg) {
            int p = wv * 16 + q * 4 + reg;
            float m = __shfl(m_row, q * 4 + reg);   // stats of row p (lane<16)
            float s = __shfl(sc_row, q * 4 + reg);
            float val = s * (acc[nt][reg] * bpn - m * wbn);
            Bu[(pbase + p) * Nn + n] = val;
            tile[p * 68 + n] = val;
        }
    }
    __syncthreads();

    // row-direction chunk carries (R6-green verbatim)
    const int nn = t & 63;
    const int seg = t >> 6;
    const int bb = blockIdx.x >> 6;
    const int jj = blockIdx.x & 63;
    const float Adv = ad_val(A[nn], snr[bb]);

    float vv[16];
    #pragma unroll
    for (int k = 0; k < 16; ++k) vv[k] = tile[(seg * 16 + k) * 68 + nn];
    float f = 0.f, bw = 0.f;
    #pragma unroll
    for (int k = 0; k < 16; ++k) f = fmaf(Adv, f, vv[k]);
    #pragma unroll
    for (int k = 15; k >= 0; --k) bw = fmaf(Adv, bw, vv[k]);
    pfs[seg][nn] = f;
    pbs[seg][nn] = bw;
    __syncthreads();

    if (t < 64) {
        float Ad16 = Adv * Adv;
        Ad16 *= Ad16; Ad16 *= Ad16; Ad16 *= Ad16;   // Adv^16
        float cf = pfs[0][t];
        #pragma unroll
        for (int i = 1; i < 4; ++i) cf = fmaf(Ad16, cf, pfs[i][t]);
        E[((0 * 8 + bb) * 64 + jj) * 64 + t] = cf;
        float cb = pbs[3][t];
        #pragma unroll
        for (int i = 2; i >= 0; --i) cb = fmaf(Ad16, cb, pbs[i][t]);
        E[((1 * 8 + bb) * 64 + (63 - jj)) * 64 + t] = cb;
    }
}

// K2: COLUMN-direction chunk carries. (R6-green verbatim.)
// 512 blocks x 64 thr, 1 wave/block.
__global__ __launch_bounds__(64) void k2_carry(
    const float* __restrict__ Bu, const float* __restrict__ A,
    const float* __restrict__ snr, float* __restrict__ E)
{
    const int lane = threadIdx.x;
    const int task = blockIdx.x;
    const int b = (task >> 6) & 7;
    const int j = task & 63;
    const float Ad = ad_val(A[lane], snr[b]);
    const float* src = Bu + ((long)b * Ll + j) * Nn + lane;
    const long stride = (long)Ww * Nn;

    float v[64];
    #pragma unroll
    for (int k = 0; k < 64; ++k) v[k] = src[k * stride];

    float s = 0.f;
    #pragma unroll
    for (int k = 0; k < 64; ++k) s = fmaf(Ad, s, v[k]);
    E[((2 * 8 + b) * 64 + j) * 64 + lane] = s;

    float sb = 0.f;
    #pragma unroll
    for (int k = 63; k >= 0; --k) sb = fmaf(Ad, sb, v[k]);
    E[((3 * 8 + b) * 64 + (63 - j)) * 64 + lane] = sb;
}

// K3: per-sequence carry prefix (exclusive scan, Ad^64 composition).
// 32 blocks (dir*8+b) x 64 thr. (R6-green verbatim.)
__global__ __launch_bounds__(64) void k3_prefix(
    const float* __restrict__ E, float* __restrict__ CT,
    const float* __restrict__ A, const float* __restrict__ snr)
{
    const int lane = threadIdx.x;
    const int db = blockIdx.x;
    const int b = db & 7;
    float Ad = ad_val(A[lane], snr[b]);
    float p64 = Ad;
    #pragma unroll
    for (int i = 0; i < 6; ++i) p64 *= p64;        // Ad^64
    const float* e = E + (long)db * 4096 + lane;
    float* ct = CT + (long)db * 4096 + lane;
    float v[64];
    #pragma unroll
    for (int k = 0; k < 64; ++k) v[k] = e[k * 64];
    float c = 0.f;
    #pragma unroll
    for (int k = 0; k < 64; ++k) {
        ct[k * 64] = c;
        c = fmaf(p64, c, v[k]);
    }
}

// K4: COLUMN apply. (R6-green verbatim.) 512 blocks x 64 thr.
__global__ __launch_bounds__(64) void k4_apply(
    const float* __restrict__ Bu, const float* __restrict__ CT,
    const float* __restrict__ A, const float* __restrict__ snr,
    float* __restrict__ Scol)
{
    const int lane = threadIdx.x;
    const int task = blockIdx.x;
    const int b = (task >> 6) & 7;
    const int j = task & 63;
    const float Ad = ad_val(A[lane], snr[b]);
    const float* src = Bu + ((long)b * Ll + j) * Nn + lane;
    const long stride = (long)Ww * Nn;
    const float cf = CT[((2 * 8 + b) * 64 + j) * 64 + lane];
    const float cb = CT[((3 * 8 + b) * 64 + (63 - j)) * 64 + lane];

    float v[64];
    #pragma unroll
    for (int k = 0; k < 64; ++k) v[k] = src[k * stride];

    float hf[64];
    float h = cf;
    #pragma unroll
    for (int k = 0; k < 64; ++k) { h = fmaf(Ad, h, v[k]); hf[k] = h; }

    float* out0 = Scol + ((long)b * Ll + j) * Nn + lane;
    float sb = cb;
    #pragma unroll
    for (int k = 63; k >= 0; --k) {
        sb = fmaf(Ad, sb, v[k]);
        out0[k * stride] = hf[k] + sb;
    }
}

// K5: row apply (vv direct from global, R10-green) + MFMA out-projection.
// NOW with the 16 Woh/Wol fragment loads hoisted ABOVE the apply phase so
// their latency hides under the apply compute. Bit-identical arithmetic.
// 512 blocks x 256 thr.
__global__ __launch_bounds__(256) void k5_gemm_out(
    const float* __restrict__ Bu, const float* __restrict__ Scol,
    const float* __restrict__ CT, const float* __restrict__ A,
    const float* __restrict__ snr,
    const float* __restrict__ x, const __bf16* __restrict__ Woh,
    const __bf16* __restrict__ Wol, const float* __restrict__ Dp,
    const float* __restrict__ Mst, const float* __restrict__ Sst,
    float* __restrict__ out)
{
    __shared__ float smem[64 * 260];    // S tile (stride 68) -> out tile (260)
    __shared__ float pfs[4][64], pbs[4][64];
    const int t = threadIdx.x;
    const int lane = t & 63;
    const int wv = __builtin_amdgcn_readfirstlane(t >> 6);
    const long pbase = (long)blockIdx.x * 64;
    const int q = lane >> 4;
    const int mi = lane & 15;

    // hoisted GEMM B-fragment loads (address depends only on wv/lane)
    v8bf bh[2][4], bl[2][4];
    #pragma unroll
    for (int kt = 0; kt < 2; ++kt)
        #pragma unroll
        for (int nt = 0; nt < 4; ++nt) {
            long wo = ((long)(kt * 16 + wv * 4 + nt) * 64 + lane) * 8;
            bh[kt][nt] = *(const v8bf*)(Woh + wo);
            bl[kt][nt] = *(const v8bf*)(Wol + wo);
        }

    // ---- row-direction seeded apply; vv straight from global (coalesced) ----
    const int nn = t & 63;
    const int seg = wv;                 // wave-uniform
    const int bb = blockIdx.x >> 6;
    const int jj = blockIdx.x & 63;
    const float Adv = ad_val(A[nn], snr[bb]);
    float Ad16 = Adv * Adv; Ad16 *= Ad16; Ad16 *= Ad16; Ad16 *= Ad16;
    const float cf  = CT[((0 * 8 + bb) * 64 + jj) * 64 + nn];
    const float cbg = CT[((1 * 8 + bb) * 64 + (63 - jj)) * 64 + nn];

    float vv[16], sc[16];
    const float* bup = Bu + (pbase + seg * 16) * Nn + nn;
    #pragma unroll
    for (int k = 0; k < 16; ++k) vv[k] = bup[k * 64];
    const float* scp = Scol + (pbase + seg * 16) * Nn + nn;
    #pragma unroll
    for (int k = 0; k < 16; ++k) sc[k] = scp[k * 64];

    float f = 0.f, bw = 0.f;
    #pragma unroll
    for (int k = 0; k < 16; ++k) f = fmaf(Adv, f, vv[k]);
    #pragma unroll
    for (int k = 15; k >= 0; --k) bw = fmaf(Adv, bw, vv[k]);
    pfs[seg][nn] = f;
    pbs[seg][nn] = bw;
    __syncthreads();

    float hseed = cf;
    for (int i = 0; i < seg; ++i) hseed = fmaf(Ad16, hseed, pfs[i][nn]);
    float bseed = cbg;
    for (int i = 3; i > seg; --i) bseed = fmaf(Ad16, bseed, pbs[i][nn]);

    float hf[16];
    float h = hseed;
    #pragma unroll
    for (int k = 0; k < 16; ++k) { h = fmaf(Adv, h, vv[k]); hf[k] = h; }
    float sb = bseed;
    #pragma unroll
    for (int k = 15; k >= 0; --k) {
        sb = fmaf(Adv, sb, vv[k]);
        smem[(seg * 16 + k) * 68 + nn] = hf[k] + sb + sc[k];
    }
    __syncthreads();

    // ---- GEMM (same MFMA order; fragments from preloaded registers) ----
    f32x4 acc[4][4];
    #pragma unroll
    for (int mt = 0; mt < 4; ++mt)
        #pragma unroll
        for (int nt = 0; nt < 4; ++nt) acc[mt][nt] = (f32x4){0.f, 0.f, 0.f, 0.f};

    #pragma unroll
    for (int kt = 0; kt < 2; ++kt) {
        #pragma unroll
        for (int mt = 0; mt < 4; ++mt) {
            const float* ar = &smem[(mt * 16 + mi) * 68 + q * 8 + kt * 32];
            v8bf sh, sl;
            #pragma unroll
            for (int j = 0; j < 8; ++j) {
                float sv = ar[j];
                __bf16 hh = (__bf16)sv;
                sh[j] = hh;
                sl[j] = (__bf16)(sv - (float)hh);
            }
            #pragma unroll
            for (int nt = 0; nt < 4; ++nt) {
                acc[mt][nt] = __builtin_amdgcn_mfma_f32_16x16x32_bf16(sh, bh[kt][nt], acc[mt][nt], 0, 0, 0);
                acc[mt][nt] = __builtin_amdgcn_mfma_f32_16x16x32_bf16(sl, bh[kt][nt], acc[mt][nt], 0, 0, 0);
                acc[mt][nt] = __builtin_amdgcn_mfma_f32_16x16x32_bf16(sh, bl[kt][nt], acc[mt][nt], 0, 0, 0);
            }
        }
    }
    __syncthreads();                    // S tile dead; reuse smem as out tile
    #pragma unroll
    for (int mt = 0; mt < 4; ++mt)
        #pragma unroll
        for (int nt = 0; nt < 4; ++nt) {
            int c = wv * 64 + nt * 16 + mi;
            #pragma unroll
            for (int reg = 0; reg < 4; ++reg)
                smem[(mt * 16 + q * 4 + reg) * 260 + c] = acc[mt][nt][reg];
        }
    __syncthreads();

    // epilogue: out = acc + D*z, fully coalesced float4 (p wave-uniform per i)
    const float4* xg = (const float4*)(x + pbase * Cc);
    float4* og = (float4*)(out + pbase * Cc);
    const float4 dv = ((const float4*)Dp)[lane];
    #pragma unroll 4
    for (int i = 0; i < 16; ++i) {
        int fi = i * 256 + t;           // p = i*4+wv (wave-uniform), c4 = lane
        int p = i * 4 + wv;
        float4 v = *(const float4*)&smem[p * 260 + lane * 4];
        float m = Mst[pbase + p], s = Sst[pbase + p];
        float4 xv = xg[fi];
        og[fi] = make_float4(v.x + dv.x * ((xv.x - m) * s),
                             v.y + dv.y * ((xv.y - m) * s),
                             v.z + dv.z * ((xv.z - m) * s),
                             v.w + dv.w * ((xv.w - m) * s));
    }
}

extern "C" void kernel_launch(void* const* d_in, const int* in_sizes, int n_in,
                              void* d_out, int out_size, void* d_ws, size_t ws_size,
                              hipStream_t stream)
{
    const float* x    = (const float*)d_in[0];
    const float* snr  = (const float*)d_in[1];
    const float* A    = (const float*)d_in[2];
    const float* Bp   = (const float*)d_in[3];
    const float* Cp   = (const float*)d_in[4];
    const float* Dp   = (const float*)d_in[5];
    const float* Win  = (const float*)d_in[6];
    const float* Wout = (const float*)d_in[7];
    float* out = (float*)d_out;

    char* ws = (char*)d_ws;
    float*  Bu   = (float*)(ws);                                        // 8 MiB
    float*  Scol = (float*)(ws + (size_t)8  * 1024 * 1024);             // 8 MiB
    float*  E    = (float*)(ws + (size_t)16 * 1024 * 1024);             // 512 KiB
    float*  CT   = (float*)(ws + (size_t)16 * 1024 * 1024 + 512*1024);  // 512 KiB
    float*  Mst  = (float*)(ws + (size_t)17 * 1024 * 1024);             // 128 KiB
    float*  Sst  = (float*)(ws + (size_t)17 * 1024 * 1024 + 128*1024);  // 128 KiB
    char*   wbase = ws + (size_t)17 * 1024 * 1024 + 512 * 1024;
    __bf16* Wh   = (__bf16*)(wbase);                                    // 32 KiB
    __bf16* Wl   = (__bf16*)(wbase + 32 * 1024);                        // 32 KiB
    __bf16* Woh  = (__bf16*)(wbase + 64 * 1024);                        // 32 KiB
    __bf16* Wol  = (__bf16*)(wbase + 96 * 1024);                        // 32 KiB
    float*  WB   = (float*)(wbase + 128 * 1024);                        // 256 B

    hipLaunchKernelGGL(k0_weights,  dim3(9),   dim3(256), 0, stream, Win, Wout, Bp, Cp, Wh, Wl, Woh, Wol, WB);
    hipLaunchKernelGGL(k1_ln_gemm,  dim3(512), dim3(256), 0, stream, x, Wh, Wl, Bp, WB, A, snr, Bu, E, Mst, Sst);
    hipLaunchKernelGGL(k2_carry,    dim3(512), dim3(64),  0, stream, Bu, A, snr, E);
    hipLaunchKernelGGL(k3_prefix,   dim3(32),  dim3(64),  0, stream, E, CT, A, snr);
    hipLaunchKernelGGL(k4_apply,    dim3(512), dim3(64),  0, stream, Bu, CT, A, snr, Scol);
    hipLaunchKernelGGL(k5_gemm_out, dim3(512), dim3(256), 0, stream, Bu, Scol, CT, A, snr, x, Woh, Wol, Dp, Mst, Sst, out);
}

// Round 12
// 129.302 us; speedup vs baseline: 1.0001x; 1.0001x over previous
//
#include <hip/hip_runtime.h>
#include <hip/hip_bf16.h>
#include <math.h>

#define Bsz 8
#define Hh 64
#define Ww 64
#define Cc 256
#define Nn 64
#define Ll 4096      /* Hh*Ww */
#define EPSf 1e-5f

typedef __bf16 v8bf __attribute__((ext_vector_type(8)));
typedef float  f32x4 __attribute__((ext_vector_type(4)));

__device__ __forceinline__ float ad_val(float a, float snr) {
    float s = fminf(fmaxf(snr, 0.f), 1.f);
    float scale = 0.6f + 0.4f * s;
    float v = tanhf(a) * scale;
    return fminf(fmaxf(v, -0.99f), 0.99f);
}

// K0: weights -> bf16 MFMA B-fragment order. (R2-proven, verbatim.)
__global__ __launch_bounds__(256) void k0_weights(
    const float* __restrict__ Win, const float* __restrict__ Wout,
    const float* __restrict__ Bp, const float* __restrict__ Cp,
    __bf16* __restrict__ Wh, __bf16* __restrict__ Wl,
    __bf16* __restrict__ Woh, __bf16* __restrict__ Wol,
    float* __restrict__ WB)
{
    const int t = threadIdx.x;
    const int blk = blockIdx.x;
    if (blk < 4) {
        for (int idx = blk * 512 + t; idx < blk * 512 + 512; idx += 256) {
            int tile = idx >> 6, lane = idx & 63;
            int kt = tile >> 2, nt = tile & 3;
            int q = lane >> 4, n = nt * 16 + (lane & 15);
            #pragma unroll
            for (int j = 0; j < 8; ++j) {
                int k = kt * 32 + q * 8 + j;
                float w = Win[n * Cc + k];
                __bf16 h = (__bf16)w;
                Wh[idx * 8 + j] = h;
                Wl[idx * 8 + j] = (__bf16)(w - (float)h);
            }
        }
    } else if (blk < 8) {
        for (int idx = (blk - 4) * 512 + t; idx < (blk - 4) * 512 + 512; idx += 256) {
            int tile = idx >> 6, lane = idx & 63;
            int kt = tile >> 4, ntg = tile & 15;
            int q = lane >> 4, c = ntg * 16 + (lane & 15);
            #pragma unroll
            for (int j = 0; j < 8; ++j) {
                int k = kt * 32 + q * 8 + j;
                float w = Wout[c * Nn + k] * 0.25f * Cp[k];
                __bf16 h = (__bf16)w;
                Woh[idx * 8 + j] = h;
                Wol[idx * 8 + j] = (__bf16)(w - (float)h);
            }
        }
    } else {
        __shared__ float wtmp[256];
        int n = t >> 2, qd = t & 3;
        float s = 0.f;
        const float* wr = Win + (long)n * Cc + qd * 64;
        for (int i = 0; i < 64; ++i) s += wr[i];
        wtmp[t] = s;
        __syncthreads();
        if (t < 64)
            WB[t] = (wtmp[t*4] + wtmp[t*4+1] + wtmp[t*4+2] + wtmp[t*4+3]) * Bp[t];
    }
}

// K1: MFMA input projection, LN stats fused into GEMM A-loads.
// (R11-green verbatim.) 512 blocks x 256 thr.
__global__ __launch_bounds__(256) void k1_ln_gemm(
    const float* __restrict__ x, const __bf16* __restrict__ Wh,
    const __bf16* __restrict__ Wl, const float* __restrict__ Bp,
    const float* __restrict__ WB, const float* __restrict__ A,
    const float* __restrict__ snr,
    float* __restrict__ Bu, float* __restrict__ E,
    float* __restrict__ Mst, float* __restrict__ Sst)
{
    __shared__ float tile[64 * 68];
    __shared__ float pfs[4][64], pbs[4][64];
    const int t = threadIdx.x;
    const int lane = t & 63;
    const int wv = __builtin_amdgcn_readfirstlane(t >> 6);
    const long pbase = (long)blockIdx.x * 64;
    const float* xt = x + pbase * Cc;

    const int q = lane >> 4;
    const int mi = lane & 15;
    const float* xa = xt + (long)(wv * 16 + mi) * Cc + q * 8;

    // load burst: all 64 x floats for this lane (16 independent float4 loads)
    float4 axv[16];
    #pragma unroll
    for (int kt = 0; kt < 8; ++kt) {
        axv[kt * 2]     = *(const float4*)(xa + kt * 32);
        axv[kt * 2 + 1] = *(const float4*)(xa + kt * 32 + 4);
    }

    f32x4 acc[4];
    #pragma unroll
    for (int nt = 0; nt < 4; ++nt) acc[nt] = (f32x4){0.f, 0.f, 0.f, 0.f};
    float sacc = 0.f, qacc = 0.f;       // LN partial sums for row wv*16+mi

    #pragma unroll
    for (int kt = 0; kt < 8; ++kt) {
        float4 a0 = axv[kt * 2];
        float4 a1 = axv[kt * 2 + 1];
        float av[8] = {a0.x, a0.y, a0.z, a0.w, a1.x, a1.y, a1.z, a1.w};
        v8bf ah, al;
        #pragma unroll
        for (int j = 0; j < 8; ++j) {
            sacc += av[j];
            qacc = fmaf(av[j], av[j], qacc);
            __bf16 h = (__bf16)av[j];
            ah[j] = h;
            al[j] = (__bf16)(av[j] - (float)h);
        }
        #pragma unroll
        for (int nt = 0; nt < 4; ++nt) {
            v8bf bh = *(const v8bf*)(Wh + ((long)(kt * 4 + nt) * 64 + lane) * 8);
            v8bf bl = *(const v8bf*)(Wl + ((long)(kt * 4 + nt) * 64 + lane) * 8);
            acc[nt] = __builtin_amdgcn_mfma_f32_16x16x32_bf16(ah, bh, acc[nt], 0, 0, 0);
            acc[nt] = __builtin_amdgcn_mfma_f32_16x16x32_bf16(al, bh, acc[nt], 0, 0, 0);
            acc[nt] = __builtin_amdgcn_mfma_f32_16x16x32_bf16(ah, bl, acc[nt], 0, 0, 0);
        }
    }

    // finish LN stats: reduce over the 4 lanes (q=0..3) holding row wv*16+mi
    sacc += __shfl_xor(sacc, 16);
    qacc += __shfl_xor(qacc, 16);
    sacc += __shfl_xor(sacc, 32);
    qacc += __shfl_xor(qacc, 32);
    float m_row = sacc * (1.f/256.f);
    float var = fmaxf(qacc * (1.f/256.f) - m_row * m_row, 0.f);
    float r1 = rsqrtf(var + EPSf);
    float v2 = var / (var + EPSf);
    float sc_row = r1 * rsqrtf(v2 + EPSf);
    if (lane < 16) {                     // q==0 lanes own rows wv*16+mi
        Mst[pbase + wv * 16 + mi] = m_row;
        Sst[pbase + wv * 16 + mi] = sc_row;
    }

    #pragma unroll
    for (int nt = 0; nt < 4; ++nt) {
        int n = nt * 16 + mi;
        float bpn = Bp[n];
        float wbn = WB[n];
        #pragma unroll
        for (int reg = 0; reg < 4; ++reg) {
            int p = wv * 16 + q * 4 + reg;
            float m = __shfl(m_row, q * 4 + reg);   // stats of row p (lane<16)
            float s = __shfl(sc_row, q * 4 + reg);
            float val = s * (acc[nt][reg] * bpn - m * wbn);
            Bu[(pbase + p) * Nn + n] = val;
            tile[p * 68 + n] = val;
        }
    }
    __syncthreads();

    // row-direction chunk carries (R6-green verbatim)
    const int nn = t & 63;
    const int seg = t >> 6;
    const int bb = blockIdx.x >> 6;
    const int jj = blockIdx.x & 63;
    const float Adv = ad_val(A[nn], snr[bb]);

    float vv[16];
    #pragma unroll
    for (int k = 0; k < 16; ++k) vv[k] = tile[(seg * 16 + k) * 68 + nn];
    float f = 0.f, bw = 0.f;
    #pragma unroll
    for (int k = 0; k < 16; ++k) f = fmaf(Adv, f, vv[k]);
    #pragma unroll
    for (int k = 15; k >= 0; --k) bw = fmaf(Adv, bw, vv[k]);
    pfs[seg][nn] = f;
    pbs[seg][nn] = bw;
    __syncthreads();

    if (t < 64) {
        float Ad16 = Adv * Adv;
        Ad16 *= Ad16; Ad16 *= Ad16; Ad16 *= Ad16;   // Adv^16
        float cf = pfs[0][t];
        #pragma unroll
        for (int i = 1; i < 4; ++i) cf = fmaf(Ad16, cf, pfs[i][t]);
        E[((0 * 8 + bb) * 64 + jj) * 64 + t] = cf;
        float cb = pbs[3][t];
        #pragma unroll
        for (int i = 2; i >= 0; --i) cb = fmaf(Ad16, cb, pbs[i][t]);
        E[((1 * 8 + bb) * 64 + (63 - jj)) * 64 + t] = cb;
    }
}

// K2: COLUMN-direction chunk carries. (R6-green verbatim.)
// 512 blocks x 64 thr, 1 wave/block.
__global__ __launch_bounds__(64) void k2_carry(
    const float* __restrict__ Bu, const float* __restrict__ A,
    const float* __restrict__ snr, float* __restrict__ E)
{
    const int lane = threadIdx.x;
    const int task = blockIdx.x;
    const int b = (task >> 6) & 7;
    const int j = task & 63;
    const float Ad = ad_val(A[lane], snr[b]);
    const float* src = Bu + ((long)b * Ll + j) * Nn + lane;
    const long stride = (long)Ww * Nn;

    float v[64];
    #pragma unroll
    for (int k = 0; k < 64; ++k) v[k] = src[k * stride];

    float s = 0.f;
    #pragma unroll
    for (int k = 0; k < 64; ++k) s = fmaf(Ad, s, v[k]);
    E[((2 * 8 + b) * 64 + j) * 64 + lane] = s;

    float sb = 0.f;
    #pragma unroll
    for (int k = 63; k >= 0; --k) sb = fmaf(Ad, sb, v[k]);
    E[((3 * 8 + b) * 64 + (63 - j)) * 64 + lane] = sb;
}

// K3: per-sequence carry prefix (exclusive scan, Ad^64 composition).
// 32 blocks (dir*8+b) x 64 thr. (R6-green verbatim.)
__global__ __launch_bounds__(64) void k3_prefix(
    const float* __restrict__ E, float* __restrict__ CT,
    const float* __restrict__ A, const float* __restrict__ snr)
{
    const int lane = threadIdx.x;
    const int db = blockIdx.x;
    const int b = db & 7;
    float Ad = ad_val(A[lane], snr[b]);
    float p64 = Ad;
    #pragma unroll
    for (int i = 0; i < 6; ++i) p64 *= p64;        // Ad^64
    const float* e = E + (long)db * 4096 + lane;
    float* ct = CT + (long)db * 4096 + lane;
    float v[64];
    #pragma unroll
    for (int k = 0; k < 64; ++k) v[k] = e[k * 64];
    float c = 0.f;
    #pragma unroll
    for (int k = 0; k < 64; ++k) {
        ct[k * 64] = c;
        c = fmaf(p64, c, v[k]);
    }
}

// K4: COLUMN apply. (R6-green verbatim.) 512 blocks x 64 thr.
__global__ __launch_bounds__(64) void k4_apply(
    const float* __restrict__ Bu, const float* __restrict__ CT,
    const float* __restrict__ A, const float* __restrict__ snr,
    float* __restrict__ Scol)
{
    const int lane = threadIdx.x;
    const int task = blockIdx.x;
    const int b = (task >> 6) & 7;
    const int j = task & 63;
    const float Ad = ad_val(A[lane], snr[b]);
    const float* src = Bu + ((long)b * Ll + j) * Nn + lane;
    const long stride = (long)Ww * Nn;
    const float cf = CT[((2 * 8 + b) * 64 + j) * 64 + lane];
    const float cb = CT[((3 * 8 + b) * 64 + (63 - j)) * 64 + lane];

    float v[64];
    #pragma unroll
    for (int k = 0; k < 64; ++k) v[k] = src[k * stride];

    float hf[64];
    float h = cf;
    #pragma unroll
    for (int k = 0; k < 64; ++k) { h = fmaf(Ad, h, v[k]); hf[k] = h; }

    float* out0 = Scol + ((long)b * Ll + j) * Nn + lane;
    float sb = cb;
    #pragma unroll
    for (int k = 63; k >= 0; --k) {
        sb = fmaf(Ad, sb, v[k]);
        out0[k * stride] = hf[k] + sb;
    }
}

// K5: SPLIT over output columns — 1024 blocks, each = (tile, half).
// Both halves redundantly compute the SAME row-apply S tile (identical
// inputs + instruction order => identical values); each half computes its
// 128 output columns with the same per-column MFMA sequence as before =>
// output bit-identical. LDS 66.5 -> 35.8 KB => 4 blocks/CU (2x occupancy).
__global__ __launch_bounds__(256) void k5_gemm_out(
    const float* __restrict__ Bu, const float* __restrict__ Scol,
    const float* __restrict__ CT, const float* __restrict__ A,
    const float* __restrict__ snr,
    const float* __restrict__ x, const __bf16* __restrict__ Woh,
    const __bf16* __restrict__ Wol, const float* __restrict__ Dp,
    const float* __restrict__ Mst, const float* __restrict__ Sst,
    float* __restrict__ out)
{
    __shared__ float smem[64 * 132];    // union: S tile [64][68] | out half [64][132]
    __shared__ float pfs[4][64], pbs[4][64];
    const int t = threadIdx.x;
    const int lane = t & 63;
    const int wv = __builtin_amdgcn_readfirstlane(t >> 6);
    const int tile = blockIdx.x >> 1;
    const int h = blockIdx.x & 1;       // output-column half
    const long pbase = (long)tile * 64;
    const int q = lane >> 4;
    const int mi = lane & 15;

    // hoisted GEMM B-fragment loads for THIS half's 128 columns
    v8bf bh[2][2], bl[2][2];
    #pragma unroll
    for (int kt = 0; kt < 2; ++kt)
        #pragma unroll
        for (int nt = 0; nt < 2; ++nt) {
            long wo = ((long)(kt * 16 + h * 8 + wv * 2 + nt) * 64 + lane) * 8;
            bh[kt][nt] = *(const v8bf*)(Woh + wo);
            bl[kt][nt] = *(const v8bf*)(Wol + wo);
        }

    // ---- row-direction seeded apply (identical in both halves) ----
    const int nn = t & 63;
    const int seg = wv;                 // wave-uniform
    const int bb = tile >> 6;
    const int jj = tile & 63;
    const float Adv = ad_val(A[nn], snr[bb]);
    float Ad16 = Adv * Adv; Ad16 *= Ad16; Ad16 *= Ad16; Ad16 *= Ad16;
    const float cf  = CT[((0 * 8 + bb) * 64 + jj) * 64 + nn];
    const float cbg = CT[((1 * 8 + bb) * 64 + (63 - jj)) * 64 + nn];

    float vv[16], sc[16];
    const float* bup = Bu + (pbase + seg * 16) * Nn + nn;
    #pragma unroll
    for (int k = 0; k < 16; ++k) vv[k] = bup[k * 64];
    const float* scp = Scol + (pbase + seg * 16) * Nn + nn;
    #pragma unroll
    for (int k = 0; k < 16; ++k) sc[k] = scp[k * 64];

    float f = 0.f, bw = 0.f;
    #pragma unroll
    for (int k = 0; k < 16; ++k) f = fmaf(Adv, f, vv[k]);
    #pragma unroll
    for (int k = 15; k >= 0; --k) bw = fmaf(Adv, bw, vv[k]);
    pfs[seg][nn] = f;
    pbs[seg][nn] = bw;
    __syncthreads();

    float hseed = cf;
    for (int i = 0; i < seg; ++i) hseed = fmaf(Ad16, hseed, pfs[i][nn]);
    float bseed = cbg;
    for (int i = 3; i > seg; --i) bseed = fmaf(Ad16, bseed, pbs[i][nn]);

    float hf[16];
    float hh = hseed;
    #pragma unroll
    for (int k = 0; k < 16; ++k) { hh = fmaf(Adv, hh, vv[k]); hf[k] = hh; }
    float sb = bseed;
    #pragma unroll
    for (int k = 15; k >= 0; --k) {
        sb = fmaf(Adv, sb, vv[k]);
        smem[(seg * 16 + k) * 68 + nn] = hf[k] + sb + sc[k];
    }
    __syncthreads();

    // ---- GEMM: this half's 128 columns (same MFMA order per column) ----
    f32x4 acc[4][2];
    #pragma unroll
    for (int mt = 0; mt < 4; ++mt)
        #pragma unroll
        for (int nt = 0; nt < 2; ++nt) acc[mt][nt] = (f32x4){0.f, 0.f, 0.f, 0.f};

    #pragma unroll
    for (int kt = 0; kt < 2; ++kt) {
        #pragma unroll
        for (int mt = 0; mt < 4; ++mt) {
            const float* ar = &smem[(mt * 16 + mi) * 68 + q * 8 + kt * 32];
            v8bf sh, sl;
            #pragma unroll
            for (int j = 0; j < 8; ++j) {
                float sv = ar[j];
                __bf16 hv = (__bf16)sv;
                sh[j] = hv;
                sl[j] = (__bf16)(sv - (float)hv);
            }
            #pragma unroll
            for (int nt = 0; nt < 2; ++nt) {
                acc[mt][nt] = __builtin_amdgcn_mfma_f32_16x16x32_bf16(sh, bh[kt][nt], acc[mt][nt], 0, 0, 0);
                acc[mt][nt] = __builtin_amdgcn_mfma_f32_16x16x32_bf16(sl, bh[kt][nt], acc[mt][nt], 0, 0, 0);
                acc[mt][nt] = __builtin_amdgcn_mfma_f32_16x16x32_bf16(sh, bl[kt][nt], acc[mt][nt], 0, 0, 0);
            }
        }
    }
    __syncthreads();                    // S tile dead; reuse smem as out half-tile
    #pragma unroll
    for (int mt = 0; mt < 4; ++mt)
        #pragma unroll
        for (int nt = 0; nt < 2; ++nt) {
            int cl = wv * 32 + nt * 16 + mi;        // local col 0..127
            #pragma unroll
            for (int reg = 0; reg < 4; ++reg)
                smem[(mt * 16 + q * 4 + reg) * 132 + cl] = acc[mt][nt][reg];
        }
    __syncthreads();

    // epilogue: this half's columns, coalesced float4
    const float4* xg = (const float4*)(x + pbase * Cc);
    float4* og = (float4*)(out + pbase * Cc);
    const int c4l = t & 31;             // local float4-col 0..31
    const float4 dv = ((const float4*)Dp)[h * 32 + c4l];
    #pragma unroll 4
    for (int i = 0; i < 8; ++i) {
        int p = i * 8 + (t >> 5);       // row 0..63
        int g = p * 64 + h * 32 + c4l;  // global float4 index
        float4 v = *(const float4*)&smem[p * 132 + c4l * 4];
        float m = Mst[pbase + p], s = Sst[pbase + p];
        float4 xv = xg[g];
        og[g] = make_float4(v.x + dv.x * ((xv.x - m) * s),
                            v.y + dv.y * ((xv.y - m) * s),
                            v.z + dv.z * ((xv.z - m) * s),
                            v.w + dv.w * ((xv.w - m) * s));
    }
}

extern "C" void kernel_launch(void* const* d_in, const int* in_sizes, int n_in,
                              void* d_out, int out_size, void* d_ws, size_t ws_size,
                              hipStream_t stream)
{
    const float* x    = (const float*)d_in[0];
    const float* snr  = (const float*)d_in[1];
    const float* A    = (const float*)d_in[2];
    const float* Bp   = (const float*)d_in[3];
    const float* Cp   = (const float*)d_in[4];
    const float* Dp   = (const float*)d_in[5];
    const float* Win  = (const float*)d_in[6];
    const float* Wout = (const float*)d_in[7];
    float* out = (float*)d_out;

    char* ws = (char*)d_ws;
    float*  Bu   = (float*)(ws);                                        // 8 MiB
    float*  Scol = (float*)(ws + (size_t)8  * 1024 * 1024);             // 8 MiB
    float*  E    = (float*)(ws + (size_t)16 * 1024 * 1024);             // 512 KiB
    float*  CT   = (float*)(ws + (size_t)16 * 1024 * 1024 + 512*1024);  // 512 KiB
    float*  Mst  = (float*)(ws + (size_t)17 * 1024 * 1024);             // 128 KiB
    float*  Sst  = (float*)(ws + (size_t)17 * 1024 * 1024 + 128*1024);  // 128 KiB
    char*   wbase = ws + (size_t)17 * 1024 * 1024 + 512 * 1024;
    __bf16* Wh   = (__bf16*)(wbase);                                    // 32 KiB
    __bf16* Wl   = (__bf16*)(wbase + 32 * 1024);                        // 32 KiB
    __bf16* Woh  = (__bf16*)(wbase + 64 * 1024);                        // 32 KiB
    __bf16* Wol  = (__bf16*)(wbase + 96 * 1024);                        // 32 KiB
    float*  WB   = (float*)(wbase + 128 * 1024);                        // 256 B

    hipLaunchKernelGGL(k0_weights,  dim3(9),    dim3(256), 0, stream, Win, Wout, Bp, Cp, Wh, Wl, Woh, Wol, WB);
    hipLaunchKernelGGL(k1_ln_gemm,  dim3(512),  dim3(256), 0, stream, x, Wh, Wl, Bp, WB, A, snr, Bu, E, Mst, Sst);
    hipLaunchKernelGGL(k2_carry,    dim3(512),  dim3(64),  0, stream, Bu, A, snr, E);
    hipLaunchKernelGGL(k3_prefix,   dim3(32),   dim3(64),  0, stream, E, CT, A, snr);
    hipLaunchKernelGGL(k4_apply,    dim3(512),  dim3(64),  0, stream, Bu, CT, A, snr, Scol);
    hipLaunchKernelGGL(k5_gemm_out, dim3(1024), dim3(256), 0, stream, Bu, Scol, CT, A, snr, x, Woh, Wol, Dp, Mst, Sst, out);
}

// Round 13
// 127.534 us; speedup vs baseline: 1.0140x; 1.0139x over previous
//
#include <hip/hip_runtime.h>
#include <hip/hip_cooperative_groups.h>
#include <hip/hip_bf16.h>
#include <math.h>

namespace cg = cooperative_groups;

#define Bsz 8
#define Hh 64
#define Ww 64
#define Cc 256
#define Nn 64
#define Ll 4096      /* Hh*Ww */
#define EPSf 1e-5f

typedef __bf16 v8bf __attribute__((ext_vector_type(8)));
typedef float  f32x4 __attribute__((ext_vector_type(4)));

__device__ __forceinline__ float ad_val(float a, float snr) {
    float s = fminf(fmaxf(snr, 0.f), 1.f);
    float scale = 0.6f + 0.4f * s;
    float v = tanhf(a) * scale;
    return fminf(fmaxf(v, -0.99f), 0.99f);
}

// ======================= standalone kernels (R11-green, verbatim) ==========

__global__ __launch_bounds__(256) void k0_weights(
    const float* __restrict__ Win, const float* __restrict__ Wout,
    const float* __restrict__ Bp, const float* __restrict__ Cp,
    __bf16* __restrict__ Wh, __bf16* __restrict__ Wl,
    __bf16* __restrict__ Woh, __bf16* __restrict__ Wol,
    float* __restrict__ WB)
{
    const int t = threadIdx.x;
    const int blk = blockIdx.x;
    if (blk < 4) {
        for (int idx = blk * 512 + t; idx < blk * 512 + 512; idx += 256) {
            int tile = idx >> 6, lane = idx & 63;
            int kt = tile >> 2, nt = tile & 3;
            int q = lane >> 4, n = nt * 16 + (lane & 15);
            #pragma unroll
            for (int j = 0; j < 8; ++j) {
                int k = kt * 32 + q * 8 + j;
                float w = Win[n * Cc + k];
                __bf16 h = (__bf16)w;
                Wh[idx * 8 + j] = h;
                Wl[idx * 8 + j] = (__bf16)(w - (float)h);
            }
        }
    } else if (blk < 8) {
        for (int idx = (blk - 4) * 512 + t; idx < (blk - 4) * 512 + 512; idx += 256) {
            int tile = idx >> 6, lane = idx & 63;
            int kt = tile >> 4, ntg = tile & 15;
            int q = lane >> 4, c = ntg * 16 + (lane & 15);
            #pragma unroll
            for (int j = 0; j < 8; ++j) {
                int k = kt * 32 + q * 8 + j;
                float w = Wout[c * Nn + k] * 0.25f * Cp[k];
                __bf16 h = (__bf16)w;
                Woh[idx * 8 + j] = h;
                Wol[idx * 8 + j] = (__bf16)(w - (float)h);
            }
        }
    } else {
        __shared__ float wtmp[256];
        int n = t >> 2, qd = t & 3;
        float s = 0.f;
        const float* wr = Win + (long)n * Cc + qd * 64;
        for (int i = 0; i < 64; ++i) s += wr[i];
        wtmp[t] = s;
        __syncthreads();
        if (t < 64)
            WB[t] = (wtmp[t*4] + wtmp[t*4+1] + wtmp[t*4+2] + wtmp[t*4+3]) * Bp[t];
    }
}

__global__ __launch_bounds__(256) void k1_ln_gemm(
    const float* __restrict__ x, const __bf16* __restrict__ Wh,
    const __bf16* __restrict__ Wl, const float* __restrict__ Bp,
    const float* __restrict__ WB, const float* __restrict__ A,
    const float* __restrict__ snr,
    float* __restrict__ Bu, float* __restrict__ E,
    float* __restrict__ Mst, float* __restrict__ Sst)
{
    __shared__ float tile[64 * 68];
    __shared__ float pfs[4][64], pbs[4][64];
    const int t = threadIdx.x;
    const int lane = t & 63;
    const int wv = __builtin_amdgcn_readfirstlane(t >> 6);
    const long pbase = (long)blockIdx.x * 64;
    const float* xt = x + pbase * Cc;

    const int q = lane >> 4;
    const int mi = lane & 15;
    const float* xa = xt + (long)(wv * 16 + mi) * Cc + q * 8;

    float4 axv[16];
    #pragma unroll
    for (int kt = 0; kt < 8; ++kt) {
        axv[kt * 2]     = *(const float4*)(xa + kt * 32);
        axv[kt * 2 + 1] = *(const float4*)(xa + kt * 32 + 4);
    }

    f32x4 acc[4];
    #pragma unroll
    for (int nt = 0; nt < 4; ++nt) acc[nt] = (f32x4){0.f, 0.f, 0.f, 0.f};
    float sacc = 0.f, qacc = 0.f;

    #pragma unroll
    for (int kt = 0; kt < 8; ++kt) {
        float4 a0 = axv[kt * 2];
        float4 a1 = axv[kt * 2 + 1];
        float av[8] = {a0.x, a0.y, a0.z, a0.w, a1.x, a1.y, a1.z, a1.w};
        v8bf ah, al;
        #pragma unroll
        for (int j = 0; j < 8; ++j) {
            sacc += av[j];
            qacc = fmaf(av[j], av[j], qacc);
            __bf16 h = (__bf16)av[j];
            ah[j] = h;
            al[j] = (__bf16)(av[j] - (float)h);
        }
        #pragma unroll
        for (int nt = 0; nt < 4; ++nt) {
            v8bf bh = *(const v8bf*)(Wh + ((long)(kt * 4 + nt) * 64 + lane) * 8);
            v8bf bl = *(const v8bf*)(Wl + ((long)(kt * 4 + nt) * 64 + lane) * 8);
            acc[nt] = __builtin_amdgcn_mfma_f32_16x16x32_bf16(ah, bh, acc[nt], 0, 0, 0);
            acc[nt] = __builtin_amdgcn_mfma_f32_16x16x32_bf16(al, bh, acc[nt], 0, 0, 0);
            acc[nt] = __builtin_amdgcn_mfma_f32_16x16x32_bf16(ah, bl, acc[nt], 0, 0, 0);
        }
    }

    sacc += __shfl_xor(sacc, 16);
    qacc += __shfl_xor(qacc, 16);
    sacc += __shfl_xor(sacc, 32);
    qacc += __shfl_xor(qacc, 32);
    float m_row = sacc * (1.f/256.f);
    float var = fmaxf(qacc * (1.f/256.f) - m_row * m_row, 0.f);
    float r1 = rsqrtf(var + EPSf);
    float v2 = var / (var + EPSf);
    float sc_row = r1 * rsqrtf(v2 + EPSf);
    if (lane < 16) {
        Mst[pbase + wv * 16 + mi] = m_row;
        Sst[pbase + wv * 16 + mi] = sc_row;
    }

    #pragma unroll
    for (int nt = 0; nt < 4; ++nt) {
        int n = nt * 16 + mi;
        float bpn = Bp[n];
        float wbn = WB[n];
        #pragma unroll
        for (int reg = 0; reg < 4; ++reg) {
            int p = wv * 16 + q * 4 + reg;
            float m = __shfl(m_row, q * 4 + reg);
            float s = __shfl(sc_row, q * 4 + reg);
            float val = s * (acc[nt][reg] * bpn - m * wbn);
            Bu[(pbase + p) * Nn + n] = val;
            tile[p * 68 + n] = val;
        }
    }
    __syncthreads();

    const int nn = t & 63;
    const int seg = t >> 6;
    const int bb = blockIdx.x >> 6;
    const int jj = blockIdx.x & 63;
    const float Adv = ad_val(A[nn], snr[bb]);

    float vv[16];
    #pragma unroll
    for (int k = 0; k < 16; ++k) vv[k] = tile[(seg * 16 + k) * 68 + nn];
    float f = 0.f, bw = 0.f;
    #pragma unroll
    for (int k = 0; k < 16; ++k) f = fmaf(Adv, f, vv[k]);
    #pragma unroll
    for (int k = 15; k >= 0; --k) bw = fmaf(Adv, bw, vv[k]);
    pfs[seg][nn] = f;
    pbs[seg][nn] = bw;
    __syncthreads();

    if (t < 64) {
        float Ad16 = Adv * Adv;
        Ad16 *= Ad16; Ad16 *= Ad16; Ad16 *= Ad16;
        float cf = pfs[0][t];
        #pragma unroll
        for (int i = 1; i < 4; ++i) cf = fmaf(Ad16, cf, pfs[i][t]);
        E[((0 * 8 + bb) * 64 + jj) * 64 + t] = cf;
        float cb = pbs[3][t];
        #pragma unroll
        for (int i = 2; i >= 0; --i) cb = fmaf(Ad16, cb, pbs[i][t]);
        E[((1 * 8 + bb) * 64 + (63 - jj)) * 64 + t] = cb;
    }
}

__global__ __launch_bounds__(64) void k2_carry(
    const float* __restrict__ Bu, const float* __restrict__ A,
    const float* __restrict__ snr, float* __restrict__ E)
{
    const int lane = threadIdx.x;
    const int task = blockIdx.x;
    const int b = (task >> 6) & 7;
    const int j = task & 63;
    const float Ad = ad_val(A[lane], snr[b]);
    const float* src = Bu + ((long)b * Ll + j) * Nn + lane;
    const long stride = (long)Ww * Nn;

    float v[64];
    #pragma unroll
    for (int k = 0; k < 64; ++k) v[k] = src[k * stride];

    float s = 0.f;
    #pragma unroll
    for (int k = 0; k < 64; ++k) s = fmaf(Ad, s, v[k]);
    E[((2 * 8 + b) * 64 + j) * 64 + lane] = s;

    float sb = 0.f;
    #pragma unroll
    for (int k = 63; k >= 0; --k) sb = fmaf(Ad, sb, v[k]);
    E[((3 * 8 + b) * 64 + (63 - j)) * 64 + lane] = sb;
}

__global__ __launch_bounds__(64) void k3_prefix(
    const float* __restrict__ E, float* __restrict__ CT,
    const float* __restrict__ A, const float* __restrict__ snr)
{
    const int lane = threadIdx.x;
    const int db = blockIdx.x;
    const int b = db & 7;
    float Ad = ad_val(A[lane], snr[b]);
    float p64 = Ad;
    #pragma unroll
    for (int i = 0; i < 6; ++i) p64 *= p64;
    const float* e = E + (long)db * 4096 + lane;
    float* ct = CT + (long)db * 4096 + lane;
    float v[64];
    #pragma unroll
    for (int k = 0; k < 64; ++k) v[k] = e[k * 64];
    float c = 0.f;
    #pragma unroll
    for (int k = 0; k < 64; ++k) {
        ct[k * 64] = c;
        c = fmaf(p64, c, v[k]);
    }
}

__global__ __launch_bounds__(64) void k4_apply(
    const float* __restrict__ Bu, const float* __restrict__ CT,
    const float* __restrict__ A, const float* __restrict__ snr,
    float* __restrict__ Scol)
{
    const int lane = threadIdx.x;
    const int task = blockIdx.x;
    const int b = (task >> 6) & 7;
    const int j = task & 63;
    const float Ad = ad_val(A[lane], snr[b]);
    const float* src = Bu + ((long)b * Ll + j) * Nn + lane;
    const long stride = (long)Ww * Nn;
    const float cf = CT[((2 * 8 + b) * 64 + j) * 64 + lane];
    const float cb = CT[((3 * 8 + b) * 64 + (63 - j)) * 64 + lane];

    float v[64];
    #pragma unroll
    for (int k = 0; k < 64; ++k) v[k] = src[k * stride];

    float hf[64];
    float h = cf;
    #pragma unroll
    for (int k = 0; k < 64; ++k) { h = fmaf(Ad, h, v[k]); hf[k] = h; }

    float* out0 = Scol + ((long)b * Ll + j) * Nn + lane;
    float sb = cb;
    #pragma unroll
    for (int k = 63; k >= 0; --k) {
        sb = fmaf(Ad, sb, v[k]);
        out0[k * stride] = hf[k] + sb;
    }
}

__global__ __launch_bounds__(256) void k5_gemm_out(
    const float* __restrict__ Bu, const float* __restrict__ Scol,
    const float* __restrict__ CT, const float* __restrict__ A,
    const float* __restrict__ snr,
    const float* __restrict__ x, const __bf16* __restrict__ Woh,
    const __bf16* __restrict__ Wol, const float* __restrict__ Dp,
    const float* __restrict__ Mst, const float* __restrict__ Sst,
    float* __restrict__ out)
{
    __shared__ float smem[64 * 260];
    __shared__ float pfs[4][64], pbs[4][64];
    const int t = threadIdx.x;
    const int lane = t & 63;
    const int wv = __builtin_amdgcn_readfirstlane(t >> 6);
    const long pbase = (long)blockIdx.x * 64;
    const int q = lane >> 4;
    const int mi = lane & 15;

    v8bf bh[2][4], bl[2][4];
    #pragma unroll
    for (int kt = 0; kt < 2; ++kt)
        #pragma unroll
        for (int nt = 0; nt < 4; ++nt) {
            long wo = ((long)(kt * 16 + wv * 4 + nt) * 64 + lane) * 8;
            bh[kt][nt] = *(const v8bf*)(Woh + wo);
            bl[kt][nt] = *(const v8bf*)(Wol + wo);
        }

    const int nn = t & 63;
    const int seg = wv;
    const int bb = blockIdx.x >> 6;
    const int jj = blockIdx.x & 63;
    const float Adv = ad_val(A[nn], snr[bb]);
    float Ad16 = Adv * Adv; Ad16 *= Ad16; Ad16 *= Ad16; Ad16 *= Ad16;
    const float cf  = CT[((0 * 8 + bb) * 64 + jj) * 64 + nn];
    const float cbg = CT[((1 * 8 + bb) * 64 + (63 - jj)) * 64 + nn];

    float vv[16], sc[16];
    const float* bup = Bu + (pbase + seg * 16) * Nn + nn;
    #pragma unroll
    for (int k = 0; k < 16; ++k) vv[k] = bup[k * 64];
    const float* scp = Scol + (pbase + seg * 16) * Nn + nn;
    #pragma unroll
    for (int k = 0; k < 16; ++k) sc[k] = scp[k * 64];

    float f = 0.f, bw = 0.f;
    #pragma unroll
    for (int k = 0; k < 16; ++k) f = fmaf(Adv, f, vv[k]);
    #pragma unroll
    for (int k = 15; k >= 0; --k) bw = fmaf(Adv, bw, vv[k]);
    pfs[seg][nn] = f;
    pbs[seg][nn] = bw;
    __syncthreads();

    float hseed = cf;
    for (int i = 0; i < seg; ++i) hseed = fmaf(Ad16, hseed, pfs[i][nn]);
    float bseed = cbg;
    for (int i = 3; i > seg; --i) bseed = fmaf(Ad16, bseed, pbs[i][nn]);

    float hf[16];
    float h = hseed;
    #pragma unroll
    for (int k = 0; k < 16; ++k) { h = fmaf(Adv, h, vv[k]); hf[k] = h; }
    float sb = bseed;
    #pragma unroll
    for (int k = 15; k >= 0; --k) {
        sb = fmaf(Adv, sb, vv[k]);
        smem[(seg * 16 + k) * 68 + nn] = hf[k] + sb + sc[k];
    }
    __syncthreads();

    f32x4 acc[4][4];
    #pragma unroll
    for (int mt = 0; mt < 4; ++mt)
        #pragma unroll
        for (int nt = 0; nt < 4; ++nt) acc[mt][nt] = (f32x4){0.f, 0.f, 0.f, 0.f};

    #pragma unroll
    for (int kt = 0; kt < 2; ++kt) {
        #pragma unroll
        for (int mt = 0; mt < 4; ++mt) {
            const float* ar = &smem[(mt * 16 + mi) * 68 + q * 8 + kt * 32];
            v8bf sh, sl;
            #pragma unroll
            for (int j = 0; j < 8; ++j) {
                float sv = ar[j];
                __bf16 hh = (__bf16)sv;
                sh[j] = hh;
                sl[j] = (__bf16)(sv - (float)hh);
            }
            #pragma unroll
            for (int nt = 0; nt < 4; ++nt) {
                acc[mt][nt] = __builtin_amdgcn_mfma_f32_16x16x32_bf16(sh, bh[kt][nt], acc[mt][nt], 0, 0, 0);
                acc[mt][nt] = __builtin_amdgcn_mfma_f32_16x16x32_bf16(sl, bh[kt][nt], acc[mt][nt], 0, 0, 0);
                acc[mt][nt] = __builtin_amdgcn_mfma_f32_16x16x32_bf16(sh, bl[kt][nt], acc[mt][nt], 0, 0, 0);
            }
        }
    }
    __syncthreads();
    #pragma unroll
    for (int mt = 0; mt < 4; ++mt)
        #pragma unroll
        for (int nt = 0; nt < 4; ++nt) {
            int c = wv * 64 + nt * 16 + mi;
            #pragma unroll
            for (int reg = 0; reg < 4; ++reg)
                smem[(mt * 16 + q * 4 + reg) * 260 + c] = acc[mt][nt][reg];
        }
    __syncthreads();

    const float4* xg = (const float4*)(x + pbase * Cc);
    float4* og = (float4*)(out + pbase * Cc);
    const float4 dv = ((const float4*)Dp)[lane];
    #pragma unroll 4
    for (int i = 0; i < 16; ++i) {
        int fi = i * 256 + t;
        int p = i * 4 + wv;
        float4 v = *(const float4*)&smem[p * 260 + lane * 4];
        float m = Mst[pbase + p], s = Sst[pbase + p];
        float4 xv = xg[fi];
        og[fi] = make_float4(v.x + dv.x * ((xv.x - m) * s),
                             v.y + dv.y * ((xv.y - m) * s),
                             v.z + dv.z * ((xv.z - m) * s),
                             v.w + dv.w * ((xv.w - m) * s));
    }
}

// ======================= MEGA: all six phases, one cooperative launch ======
// Bodies are byte-copies of the standalone kernels above (role: blk=tile for
// k1/k5; task=blk, t<64 for k2/k4; blk<32, t<64 for k3). __threadfence() +
// grid.sync() between phases. LDS: smem[64*260] reused (k1 tile aliases it).
__global__ __launch_bounds__(256, 2) void mega(
    const float* __restrict__ x, const float* __restrict__ snr,
    const float* __restrict__ A, const float* __restrict__ Bp,
    const float* __restrict__ Cp, const float* __restrict__ Dp,
    const float* __restrict__ Win, const float* __restrict__ Wout,
    __bf16* __restrict__ Wh, __bf16* __restrict__ Wl,
    __bf16* __restrict__ Woh, __bf16* __restrict__ Wol,
    float* __restrict__ WB,
    float* __restrict__ Bu, float* __restrict__ Scol,
    float* __restrict__ E, float* __restrict__ CT,
    float* __restrict__ Mst, float* __restrict__ Sst,
    float* __restrict__ out)
{
    cg::grid_group grid = cg::this_grid();
    __shared__ float smem[64 * 260];
    __shared__ float pfs[4][64], pbs[4][64];
    const int t = threadIdx.x;
    const int lane = t & 63;
    const int wv = __builtin_amdgcn_readfirstlane(t >> 6);
    const int blk = blockIdx.x;
    const long pbase = (long)blk * 64;
    const int q = lane >> 4;
    const int mi = lane & 15;
    const int nn = t & 63;
    const int bb = blk >> 6;
    const int jj = blk & 63;

    // ---- P0: weights (k0 body; blk 0..8) ----
    if (blk < 4) {
        for (int idx = blk * 512 + t; idx < blk * 512 + 512; idx += 256) {
            int tile = idx >> 6, ln = idx & 63;
            int kt = tile >> 2, nt = tile & 3;
            int qq = ln >> 4, n = nt * 16 + (ln & 15);
            #pragma unroll
            for (int j = 0; j < 8; ++j) {
                int k = kt * 32 + qq * 8 + j;
                float w = Win[n * Cc + k];
                __bf16 h = (__bf16)w;
                Wh[idx * 8 + j] = h;
                Wl[idx * 8 + j] = (__bf16)(w - (float)h);
            }
        }
    } else if (blk < 8) {
        for (int idx = (blk - 4) * 512 + t; idx < (blk - 4) * 512 + 512; idx += 256) {
            int tile = idx >> 6, ln = idx & 63;
            int kt = tile >> 4, ntg = tile & 15;
            int qq = ln >> 4, c = ntg * 16 + (ln & 15);
            #pragma unroll
            for (int j = 0; j < 8; ++j) {
                int k = kt * 32 + qq * 8 + j;
                float w = Wout[c * Nn + k] * 0.25f * Cp[k];
                __bf16 h = (__bf16)w;
                Woh[idx * 8 + j] = h;
                Wol[idx * 8 + j] = (__bf16)(w - (float)h);
            }
        }
    } else if (blk == 8) {
        float* wtmp = smem;
        int n = t >> 2, qd = t & 3;
        float s = 0.f;
        const float* wr = Win + (long)n * Cc + qd * 64;
        for (int i = 0; i < 64; ++i) s += wr[i];
        wtmp[t] = s;
        __syncthreads();
        if (t < 64)
            WB[t] = (wtmp[t*4] + wtmp[t*4+1] + wtmp[t*4+2] + wtmp[t*4+3]) * Bp[t];
        __syncthreads();
    }
    __threadfence();
    grid.sync();

    // ---- P1: k1 body (tile aliases smem, stride 68) ----
    {
        float* tile = smem;
        const float* xt = x + pbase * Cc;
        const float* xa = xt + (long)(wv * 16 + mi) * Cc + q * 8;

        float4 axv[16];
        #pragma unroll
        for (int kt = 0; kt < 8; ++kt) {
            axv[kt * 2]     = *(const float4*)(xa + kt * 32);
            axv[kt * 2 + 1] = *(const float4*)(xa + kt * 32 + 4);
        }

        f32x4 acc[4];
        #pragma unroll
        for (int nt = 0; nt < 4; ++nt) acc[nt] = (f32x4){0.f, 0.f, 0.f, 0.f};
        float sacc = 0.f, qacc = 0.f;

        #pragma unroll
        for (int kt = 0; kt < 8; ++kt) {
            float4 a0 = axv[kt * 2];
            float4 a1 = axv[kt * 2 + 1];
            float av[8] = {a0.x, a0.y, a0.z, a0.w, a1.x, a1.y, a1.z, a1.w};
            v8bf ah, al;
            #pragma unroll
            for (int j = 0; j < 8; ++j) {
                sacc += av[j];
                qacc = fmaf(av[j], av[j], qacc);
                __bf16 h = (__bf16)av[j];
                ah[j] = h;
                al[j] = (__bf16)(av[j] - (float)h);
            }
            #pragma unroll
            for (int nt = 0; nt < 4; ++nt) {
                v8bf bh = *(const v8bf*)(Wh + ((long)(kt * 4 + nt) * 64 + lane) * 8);
                v8bf bl = *(const v8bf*)(Wl + ((long)(kt * 4 + nt) * 64 + lane) * 8);
                acc[nt] = __builtin_amdgcn_mfma_f32_16x16x32_bf16(ah, bh, acc[nt], 0, 0, 0);
                acc[nt] = __builtin_amdgcn_mfma_f32_16x16x32_bf16(al, bh, acc[nt], 0, 0, 0);
                acc[nt] = __builtin_amdgcn_mfma_f32_16x16x32_bf16(ah, bl, acc[nt], 0, 0, 0);
            }
        }

        sacc += __shfl_xor(sacc, 16);
        qacc += __shfl_xor(qacc, 16);
        sacc += __shfl_xor(sacc, 32);
        qacc += __shfl_xor(qacc, 32);
        float m_row = sacc * (1.f/256.f);
        float var = fmaxf(qacc * (1.f/256.f) - m_row * m_row, 0.f);
        float r1 = rsqrtf(var + EPSf);
        float v2 = var / (var + EPSf);
        float sc_row = r1 * rsqrtf(v2 + EPSf);
        if (lane < 16) {
            Mst[pbase + wv * 16 + mi] = m_row;
            Sst[pbase + wv * 16 + mi] = sc_row;
        }

        #pragma unroll
        for (int nt = 0; nt < 4; ++nt) {
            int n = nt * 16 + mi;
            float bpn = Bp[n];
            float wbn = WB[n];
            #pragma unroll
            for (int reg = 0; reg < 4; ++reg) {
                int p = wv * 16 + q * 4 + reg;
                float m = __shfl(m_row, q * 4 + reg);
                float s = __shfl(sc_row, q * 4 + reg);
                float val = s * (acc[nt][reg] * bpn - m * wbn);
                Bu[(pbase + p) * Nn + n] = val;
                tile[p * 68 + n] = val;
            }
        }
        __syncthreads();

        const int seg = t >> 6;
        const float Adv = ad_val(A[nn], snr[bb]);
        float vv[16];
        #pragma unroll
        for (int k = 0; k < 16; ++k) vv[k] = tile[(seg * 16 + k) * 68 + nn];
        float f = 0.f, bw = 0.f;
        #pragma unroll
        for (int k = 0; k < 16; ++k) f = fmaf(Adv, f, vv[k]);
        #pragma unroll
        for (int k = 15; k >= 0; --k) bw = fmaf(Adv, bw, vv[k]);
        pfs[seg][nn] = f;
        pbs[seg][nn] = bw;
        __syncthreads();

        if (t < 64) {
            float Ad16 = Adv * Adv;
            Ad16 *= Ad16; Ad16 *= Ad16; Ad16 *= Ad16;
            float cf = pfs[0][t];
            #pragma unroll
            for (int i = 1; i < 4; ++i) cf = fmaf(Ad16, cf, pfs[i][t]);
            E[((0 * 8 + bb) * 64 + jj) * 64 + t] = cf;
            float cb = pbs[3][t];
            #pragma unroll
            for (int i = 2; i >= 0; --i) cb = fmaf(Ad16, cb, pbs[i][t]);
            E[((1 * 8 + bb) * 64 + (63 - jj)) * 64 + t] = cb;
        }
    }
    __threadfence();
    grid.sync();

    // ---- P2: k2 body (task = blk; one wave) ----
    if (t < 64) {
        const int b = (blk >> 6) & 7;
        const int j = blk & 63;
        const float Ad = ad_val(A[t], snr[b]);
        const float* src = Bu + ((long)b * Ll + j) * Nn + t;
        const long stride = (long)Ww * Nn;

        float v[64];
        #pragma unroll
        for (int k = 0; k < 64; ++k) v[k] = src[k * stride];

        float s = 0.f;
        #pragma unroll
        for (int k = 0; k < 64; ++k) s = fmaf(Ad, s, v[k]);
        E[((2 * 8 + b) * 64 + j) * 64 + t] = s;

        float sb = 0.f;
        #pragma unroll
        for (int k = 63; k >= 0; --k) sb = fmaf(Ad, sb, v[k]);
        E[((3 * 8 + b) * 64 + (63 - j)) * 64 + t] = sb;
    }
    __threadfence();
    grid.sync();

    // ---- P3: k3 body (blk < 32; one wave) ----
    if (blk < 32 && t < 64) {
        const int db = blk;
        const int b = db & 7;
        float Ad = ad_val(A[t], snr[b]);
        float p64 = Ad;
        #pragma unroll
        for (int i = 0; i < 6; ++i) p64 *= p64;
        const float* e = E + (long)db * 4096 + t;
        float* ct = CT + (long)db * 4096 + t;
        float v[64];
        #pragma unroll
        for (int k = 0; k < 64; ++k) v[k] = e[k * 64];
        float c = 0.f;
        #pragma unroll
        for (int k = 0; k < 64; ++k) {
            ct[k * 64] = c;
            c = fmaf(p64, c, v[k]);
        }
    }
    __threadfence();
    grid.sync();

    // ---- P4: k4 body (task = blk; one wave) ----
    if (t < 64) {
        const int b = (blk >> 6) & 7;
        const int j = blk & 63;
        const float Ad = ad_val(A[t], snr[b]);
        const float* src = Bu + ((long)b * Ll + j) * Nn + t;
        const long stride = (long)Ww * Nn;
        const float cf = CT[((2 * 8 + b) * 64 + j) * 64 + t];
        const float cb = CT[((3 * 8 + b) * 64 + (63 - j)) * 64 + t];

        float v[64];
        #pragma unroll
        for (int k = 0; k < 64; ++k) v[k] = src[k * stride];

        float hf[64];
        float h = cf;
        #pragma unroll
        for (int k = 0; k < 64; ++k) { h = fmaf(Ad, h, v[k]); hf[k] = h; }

        float* out0 = Scol + ((long)b * Ll + j) * Nn + t;
        float sb = cb;
        #pragma unroll
        for (int k = 63; k >= 0; --k) {
            sb = fmaf(Ad, sb, v[k]);
            out0[k * stride] = hf[k] + sb;
        }
    }
    __threadfence();
    grid.sync();

    // ---- P5: k5 body ----
    {
        v8bf bh[2][4], bl[2][4];
        #pragma unroll
        for (int kt = 0; kt < 2; ++kt)
            #pragma unroll
            for (int nt = 0; nt < 4; ++nt) {
                long wo = ((long)(kt * 16 + wv * 4 + nt) * 64 + lane) * 8;
                bh[kt][nt] = *(const v8bf*)(Woh + wo);
                bl[kt][nt] = *(const v8bf*)(Wol + wo);
            }

        const int seg = wv;
        const float Adv = ad_val(A[nn], snr[bb]);
        float Ad16 = Adv * Adv; Ad16 *= Ad16; Ad16 *= Ad16; Ad16 *= Ad16;
        const float cf  = CT[((0 * 8 + bb) * 64 + jj) * 64 + nn];
        const float cbg = CT[((1 * 8 + bb) * 64 + (63 - jj)) * 64 + nn];

        float vv[16], sc[16];
        const float* bup = Bu + (pbase + seg * 16) * Nn + nn;
        #pragma unroll
        for (int k = 0; k < 16; ++k) vv[k] = bup[k * 64];
        const float* scp = Scol + (pbase + seg * 16) * Nn + nn;
        #pragma unroll
        for (int k = 0; k < 16; ++k) sc[k] = scp[k * 64];

        float f = 0.f, bw = 0.f;
        #pragma unroll
        for (int k = 0; k < 16; ++k) f = fmaf(Adv, f, vv[k]);
        #pragma unroll
        for (int k = 15; k >= 0; --k) bw = fmaf(Adv, bw, vv[k]);
        pfs[seg][nn] = f;
        pbs[seg][nn] = bw;
        __syncthreads();

        float hseed = cf;
        for (int i = 0; i < seg; ++i) hseed = fmaf(Ad16, hseed, pfs[i][nn]);
        float bseed = cbg;
        for (int i = 3; i > seg; --i) bseed = fmaf(Ad16, bseed, pbs[i][nn]);

        float hf[16];
        float h = hseed;
        #pragma unroll
        for (int k = 0; k < 16; ++k) { h = fmaf(Adv, h, vv[k]); hf[k] = h; }
        float sb = bseed;
        #pragma unroll
        for (int k = 15; k >= 0; --k) {
            sb = fmaf(Adv, sb, vv[k]);
            smem[(seg * 16 + k) * 68 + nn] = hf[k] + sb + sc[k];
        }
        __syncthreads();

        f32x4 acc[4][4];
        #pragma unroll
        for (int mt = 0; mt < 4; ++mt)
            #pragma unroll
            for (int nt = 0; nt < 4; ++nt) acc[mt][nt] = (f32x4){0.f, 0.f, 0.f, 0.f};

        #pragma unroll
        for (int kt = 0; kt < 2; ++kt) {
            #pragma unroll
            for (int mt = 0; mt < 4; ++mt) {
                const float* ar = &smem[(mt * 16 + mi) * 68 + q * 8 + kt * 32];
                v8bf sh, sl;
                #pragma unroll
                for (int j = 0; j < 8; ++j) {
                    float sv = ar[j];
                    __bf16 hh = (__bf16)sv;
                    sh[j] = hh;
                    sl[j] = (__bf16)(sv - (float)hh);
                }
                #pragma unroll
                for (int nt = 0; nt < 4; ++nt) {
                    acc[mt][nt] = __builtin_amdgcn_mfma_f32_16x16x32_bf16(sh, bh[kt][nt], acc[mt][nt], 0, 0, 0);
                    acc[mt][nt] = __builtin_amdgcn_mfma_f32_16x16x32_bf16(sl, bh[kt][nt], acc[mt][nt], 0, 0, 0);
                    acc[mt][nt] = __builtin_amdgcn_mfma_f32_16x16x32_bf16(sh, bl[kt][nt], acc[mt][nt], 0, 0, 0);
                }
            }
        }
        __syncthreads();
        #pragma unroll
        for (int mt = 0; mt < 4; ++mt)
            #pragma unroll
            for (int nt = 0; nt < 4; ++nt) {
                int c = wv * 64 + nt * 16 + mi;
                #pragma unroll
                for (int reg = 0; reg < 4; ++reg)
                    smem[(mt * 16 + q * 4 + reg) * 260 + c] = acc[mt][nt][reg];
            }
        __syncthreads();

        const float4* xg = (const float4*)(x + pbase * Cc);
        float4* og = (float4*)(out + pbase * Cc);
        const float4 dv = ((const float4*)Dp)[lane];
        #pragma unroll 4
        for (int i = 0; i < 16; ++i) {
            int fi = i * 256 + t;
            int p = i * 4 + wv;
            float4 v = *(const float4*)&smem[p * 260 + lane * 4];
            float m = Mst[pbase + p], s = Sst[pbase + p];
            float4 xv = xg[fi];
            og[fi] = make_float4(v.x + dv.x * ((xv.x - m) * s),
                                 v.y + dv.y * ((xv.y - m) * s),
                                 v.z + dv.z * ((xv.z - m) * s),
                                 v.w + dv.w * ((xv.w - m) * s));
        }
    }
}

extern "C" void kernel_launch(void* const* d_in, const int* in_sizes, int n_in,
                              void* d_out, int out_size, void* d_ws, size_t ws_size,
                              hipStream_t stream)
{
    const float* x    = (const float*)d_in[0];
    const float* snr  = (const float*)d_in[1];
    const float* A    = (const float*)d_in[2];
    const float* Bp   = (const float*)d_in[3];
    const float* Cp   = (const float*)d_in[4];
    const float* Dp   = (const float*)d_in[5];
    const float* Win  = (const float*)d_in[6];
    const float* Wout = (const float*)d_in[7];
    float* out = (float*)d_out;

    char* ws = (char*)d_ws;
    float*  Bu   = (float*)(ws);                                        // 8 MiB
    float*  Scol = (float*)(ws + (size_t)8  * 1024 * 1024);             // 8 MiB
    float*  E    = (float*)(ws + (size_t)16 * 1024 * 1024);             // 512 KiB
    float*  CT   = (float*)(ws + (size_t)16 * 1024 * 1024 + 512*1024);  // 512 KiB
    float*  Mst  = (float*)(ws + (size_t)17 * 1024 * 1024);             // 128 KiB
    float*  Sst  = (float*)(ws + (size_t)17 * 1024 * 1024 + 128*1024);  // 128 KiB
    char*   wbase = ws + (size_t)17 * 1024 * 1024 + 512 * 1024;
    __bf16* Wh   = (__bf16*)(wbase);                                    // 32 KiB
    __bf16* Wl   = (__bf16*)(wbase + 32 * 1024);                        // 32 KiB
    __bf16* Woh  = (__bf16*)(wbase + 64 * 1024);                        // 32 KiB
    __bf16* Wol  = (__bf16*)(wbase + 96 * 1024);                        // 32 KiB
    float*  WB   = (float*)(wbase + 128 * 1024);                        // 256 B

    // try single cooperative launch; fall back to the green 6-kernel path
    int maxActive = 0;
    hipError_t occErr = hipOccupancyMaxActiveBlocksPerMultiprocessor(
        &maxActive, reinterpret_cast<const void*>(mega), 256, 0);
    hipError_t lerr = hipErrorUnknown;
    if (occErr == hipSuccess && maxActive >= 2) {
        void* args[] = {
            (void*)&x, (void*)&snr, (void*)&A, (void*)&Bp, (void*)&Cp,
            (void*)&Dp, (void*)&Win, (void*)&Wout,
            (void*)&Wh, (void*)&Wl, (void*)&Woh, (void*)&Wol, (void*)&WB,
            (void*)&Bu, (void*)&Scol, (void*)&E, (void*)&CT,
            (void*)&Mst, (void*)&Sst, (void*)&out
        };
        lerr = hipLaunchCooperativeKernel(reinterpret_cast<void*>(mega),
                                          dim3(512), dim3(256), args, 0, stream);
    }
    if (lerr != hipSuccess) {
        (void)hipGetLastError();   // clear any launch-error state
        hipLaunchKernelGGL(k0_weights,  dim3(9),   dim3(256), 0, stream, Win, Wout, Bp, Cp, Wh, Wl, Woh, Wol, WB);
        hipLaunchKernelGGL(k1_ln_gemm,  dim3(512), dim3(256), 0, stream, x, Wh, Wl, Bp, WB, A, snr, Bu, E, Mst, Sst);
        hipLaunchKernelGGL(k2_carry,    dim3(512), dim3(64),  0, stream, Bu, A, snr, E);
        hipLaunchKernelGGL(k3_prefix,   dim3(32),  dim3(64),  0, stream, E, CT, A, snr);
        hipLaunchKernelGGL(k4_apply,    dim3(512), dim3(64),  0, stream, Bu, CT, A, snr, Scol);
        hipLaunchKernelGGL(k5_gemm_out, dim3(512), dim3(256), 0, stream, Bu, Scol, CT, A, snr, x, Woh, Wol, Dp, Mst, Sst, out);
    }
}